// Round 6
// baseline (241.696 us; speedup 1.0000x reference)
//
#include <hip/hip_runtime.h>
#include <math.h>
#include <float.h>

constexpr int D = 128;       // in_channels
constexpr int B = 512;       // batch_size (graphs)
constexpr int STEPS = 3;
constexpr int NW_IH = 3 * D * 2 * D;   // 98304 elems, Wih [3D][2D]
constexpr int NW_HH = 3 * D * D;       // 49152 elems, Whh [3D][D]
constexpr float NEG_HUGE = -3.402823466e38f;   // -FLT_MAX sentinel (finite: no NaN paths)

__device__ __forceinline__ float sigmoidf_(float x) { return 1.f / (1.f + __expf(-x)); }
// bf16 pair unpack from a uint: low halfword / high halfword -> float (exact)
__device__ __forceinline__ float bflo(unsigned int u) { return __uint_as_float(u << 16); }
__device__ __forceinline__ float bfhi(unsigned int u) { return __uint_as_float(u & 0xffff0000u); }
__device__ __forceinline__ unsigned short f2bf_rn(float f) {
    unsigned int u = __float_as_uint(f);
    u += 0x7fffu + ((u >> 16) & 1u);    // round-to-nearest-even
    return (unsigned short)(u >> 16);
}
__device__ __forceinline__ float4 ld4(const float* p) { return *(const float4*)p; }
__device__ __forceinline__ int imin_(int a, int b) { return a < b ? a : b; }

// ---------------------------------------------------------------------------
// K0 (prep): weights fp32 -> bf16 (RN) in a PACKED-TRANSPOSED layout, plus
// segment bounds via binary search on sorted batch[].
// Packed layout (per matrix): for column-group j (4 cols) and row-pair t
// (rows 2t,2t+1), the 8 bf16 {W[2t][4j..4j+3], W[2t+1][4j..4j+3]} are one
// contiguous uint4 at element (j*192 + t). GRU threads t=0..191 then read
// lane-contiguous uint4s (wave touches 16 lines = minimum for 1KB) instead
// of 1KB-strided rows (64 lines/instr). Bijection proof: flat index
// ((c>>2)*192 + (r>>1))*8 + (r&1)*4 + (c&3) covers [0, rows*cols).
// ---------------------------------------------------------------------------
__global__ __launch_bounds__(256) void k_prep(const float* __restrict__ Wih,
        const float* __restrict__ Whh, const int* __restrict__ batch, int n,
        unsigned short* __restrict__ wih_bf, unsigned short* __restrict__ whh_bf,
        int* __restrict__ seg) {
    int i = blockIdx.x * blockDim.x + threadIdx.x;
    if (i < NW_IH) {
        const int r = i >> 8, c = i & 255;            // Wih [384][256]
        const int pk = (((c >> 2) * 192 + (r >> 1)) << 3) + ((r & 1) << 2) + (c & 3);
        wih_bf[pk] = f2bf_rn(Wih[i]);
    } else if (i < NW_IH + NW_HH) {
        const int k = i - NW_IH;
        const int r = k >> 7, c = k & 127;            // Whh [384][128]
        const int pk = (((c >> 2) * 192 + (r >> 1)) << 3) + ((r & 1) << 2) + (c & 3);
        whh_bf[pk] = f2bf_rn(Whh[k]);
    }
    if (i <= B) {
        int lo = 0, hi = n;
        while (lo < hi) { int mid = (lo + hi) >> 1; if (batch[mid] < i) lo = mid + 1; else hi = mid; }
        seg[i] = lo;
    }
}

// ---------------------------------------------------------------------------
// K1 (fused Set2Set): one block of 256 threads (4 waves) per graph.
// R5 post-mortem: ~15us per GRU matvec step, dominated by 1KB-lane-stride
// weight loads (64 lines per instruction through the CU's address path).
// R6 = R5 skeleton byte-for-byte, except the GRU matvec reads the packed-
// transposed weights: per iteration one lane-contiguous uint4 per thread
// (16 lines/instr for the wave, the coalescing minimum) + one broadcast
// ds_read_b128 of q[4j..4j+3]. Same FMA count, fewer address registers.
// Everything else (depth-2 masked-tail attention pipeline, step-0 GRU skip,
// dense col map, 4-shfl combine) unchanged from the verified R5.
// ---------------------------------------------------------------------------
struct Trip { float4 a0, a1, b0, b1, c0, c1, d0, d1; };

__global__ __launch_bounds__(256, 2) void k_set2set(
        const float* __restrict__ x,
        const unsigned short* __restrict__ wih_bf,
        const unsigned short* __restrict__ whh_bf,
        const float* __restrict__ bih, const float* __restrict__ bhh,
        const int* __restrict__ seg, float* __restrict__ out) {
    __shared__ __align__(16) float s_q[2 * D];    // q_star: [q | r]
    __shared__ __align__(16) float s_h[D];
    __shared__ float s_gi[3 * D], s_gh[3 * D];
    __shared__ float sm[16], sl[16];
    __shared__ __align__(16) float rpart[4][D];   // 2 KB

    const int b = blockIdx.x;
    const int tid = threadIdx.x;
    const int start = seg[b], end = seg[b + 1];
    const int g = tid >> 4;               // node-group id 0..15
    const int s = tid & 15;               // sublane: cols [4s,4s+4) & [64+4s,64+4s+4)
    const int s4 = s * 4;

    const int len = end - start;
    const int FT = (len + 63) >> 6;       // trips incl. masked last
    const int gbase = start + g;
    const int eclamp = (len > 0) ? end - 1 : start;

    float m_run, l_run;
    float4 acc0, acc1;
    float4 q0, q1;
    Trip T0_, T1_;

    auto load_trip = [&](Trip& T, int t) {
        const int n0 = gbase + (t << 6);
        const float* p0 = x + ((size_t)imin_(n0,      eclamp) << 7) + s4;
        const float* p1 = x + ((size_t)imin_(n0 + 16, eclamp) << 7) + s4;
        const float* p2 = x + ((size_t)imin_(n0 + 32, eclamp) << 7) + s4;
        const float* p3 = x + ((size_t)imin_(n0 + 48, eclamp) << 7) + s4;
        T.a0 = ld4(p0); T.a1 = ld4(p0 + 64);
        T.b0 = ld4(p1); T.b1 = ld4(p1 + 64);
        T.c0 = ld4(p2); T.c1 = ld4(p2 + 64);
        T.d0 = ld4(p3); T.d1 = ld4(p3 + 64);
    };
    auto dot8 = [&](const float4& lo, const float4& hi) {
        float p = lo.x * q0.x;
        p = fmaf(lo.y, q0.y, p); p = fmaf(lo.z, q0.z, p); p = fmaf(lo.w, q0.w, p);
        p = fmaf(hi.x, q1.x, p); p = fmaf(hi.y, q1.y, p);
        p = fmaf(hi.z, q1.z, p); p = fmaf(hi.w, q1.w, p);
        return p;
    };
    auto compute_core = [&](const Trip& T, bool masked, int t) {
        float p0 = dot8(T.a0, T.a1);
        float p1 = dot8(T.b0, T.b1);
        float p2 = dot8(T.c0, T.c1);
        float p3 = dot8(T.d0, T.d1);
        p0 += __shfl_xor(p0, 1, 64); p1 += __shfl_xor(p1, 1, 64);
        p2 += __shfl_xor(p2, 1, 64); p3 += __shfl_xor(p3, 1, 64);
        p0 += __shfl_xor(p0, 2, 64); p1 += __shfl_xor(p1, 2, 64);
        p2 += __shfl_xor(p2, 2, 64); p3 += __shfl_xor(p3, 2, 64);
        p0 += __shfl_xor(p0, 4, 64); p1 += __shfl_xor(p1, 4, 64);
        p2 += __shfl_xor(p2, 4, 64); p3 += __shfl_xor(p3, 4, 64);
        p0 += __shfl_xor(p0, 8, 64); p1 += __shfl_xor(p1, 8, 64);
        p2 += __shfl_xor(p2, 8, 64); p3 += __shfl_xor(p3, 8, 64);
        bool m0 = true, m1 = true, m2 = true, m3 = true;
        float h0 = p0, h1 = p1, h2 = p2, h3 = p3;
        if (masked) {
            const int n0 = gbase + (t << 6);
            m0 = n0 < end; m1 = n0 + 16 < end; m2 = n0 + 32 < end; m3 = n0 + 48 < end;
            h0 = m0 ? p0 : NEG_HUGE; h1 = m1 ? p1 : NEG_HUGE;
            h2 = m2 ? p2 : NEG_HUGE; h3 = m3 ? p3 : NEG_HUGE;
        }
        float nm = fmaxf(m_run, fmaxf(fmaxf(h0, h1), fmaxf(h2, h3)));
        float sc = __expf(m_run - nm);            // 0 while m_run sentinel
        float e0 = __expf(p0 - nm), e1 = __expf(p1 - nm);
        float e2 = __expf(p2 - nm), e3 = __expf(p3 - nm);
        if (masked) {
            e0 = m0 ? e0 : 0.f; e1 = m1 ? e1 : 0.f;
            e2 = m2 ? e2 : 0.f; e3 = m3 ? e3 : 0.f;
        }
        l_run = fmaf(l_run, sc, (e0 + e1) + (e2 + e3));
        acc0.x = fmaf(acc0.x, sc, fmaf(e0, T.a0.x, fmaf(e1, T.b0.x, fmaf(e2, T.c0.x, e3 * T.d0.x))));
        acc0.y = fmaf(acc0.y, sc, fmaf(e0, T.a0.y, fmaf(e1, T.b0.y, fmaf(e2, T.c0.y, e3 * T.d0.y))));
        acc0.z = fmaf(acc0.z, sc, fmaf(e0, T.a0.z, fmaf(e1, T.b0.z, fmaf(e2, T.c0.z, e3 * T.d0.z))));
        acc0.w = fmaf(acc0.w, sc, fmaf(e0, T.a0.w, fmaf(e1, T.b0.w, fmaf(e2, T.c0.w, e3 * T.d0.w))));
        acc1.x = fmaf(acc1.x, sc, fmaf(e0, T.a1.x, fmaf(e1, T.b1.x, fmaf(e2, T.c1.x, e3 * T.d1.x))));
        acc1.y = fmaf(acc1.y, sc, fmaf(e0, T.a1.y, fmaf(e1, T.b1.y, fmaf(e2, T.c1.y, e3 * T.d1.y))));
        acc1.z = fmaf(acc1.z, sc, fmaf(e0, T.a1.z, fmaf(e1, T.b1.z, fmaf(e2, T.c1.z, e3 * T.d1.z))));
        acc1.w = fmaf(acc1.w, sc, fmaf(e0, T.a1.w, fmaf(e1, T.b1.w, fmaf(e2, T.c1.w, e3 * T.d1.w))));
        m_run = nm;
    };
    auto compute  = [&](const Trip& T)        { compute_core(T, false, 0); };
    auto computeM = [&](const Trip& T, int t) { compute_core(T, true,  t); };

    if (tid < 2 * D) s_q[tid] = 0.f;
    if (tid < D) s_h[tid] = 0.f;
    __syncthreads();

    for (int step = 0; step < STEPS; ++step) {
        // prefetch trip 0 of x under the GRU (x is step-invariant; no LDS dep)
        if (FT > 0) load_trip(T0_, 0);

        if (step == 0) {
            // q_star = 0 and h = 0: gi = b_ih, gh = b_hh exactly -> skip matvec
            for (int i = tid; i < 3 * D; i += 256) { s_gi[i] = bih[i]; s_gh[i] = bhh[i]; }
        } else if (tid < 192) {
            // ---- GRU gate rows 2t,2t+1: packed-transposed weights ----
            // per iter: one lane-contiguous uint4 (wave = 1KB dense) + one
            // broadcast float4 of q/h from LDS + 8 fma.
            const int r0 = tid * 2;
            float gi0 = bih[r0], gi1 = bih[r0 + 1];
            float gh0 = bhh[r0], gh1 = bhh[r0 + 1];
            const uint4* wp = (const uint4*)wih_bf + tid;   // + j*192 per iter
            const uint4* vp = (const uint4*)whh_bf + tid;
            const float4* q4 = (const float4*)s_q;
            const float4* h4 = (const float4*)s_h;
#pragma unroll 4
            for (int j = 0; j < 64; ++j) {        // 256 cols of Wih, 4/iter
                const uint4 w = wp[j * 192];
                const float4 qv = q4[j];
                gi0 = fmaf(bflo(w.x), qv.x, gi0); gi0 = fmaf(bfhi(w.x), qv.y, gi0);
                gi0 = fmaf(bflo(w.y), qv.z, gi0); gi0 = fmaf(bfhi(w.y), qv.w, gi0);
                gi1 = fmaf(bflo(w.z), qv.x, gi1); gi1 = fmaf(bfhi(w.z), qv.y, gi1);
                gi1 = fmaf(bflo(w.w), qv.z, gi1); gi1 = fmaf(bfhi(w.w), qv.w, gi1);
            }
#pragma unroll 4
            for (int j = 0; j < 32; ++j) {        // 128 cols of Whh, 4/iter
                const uint4 w = vp[j * 192];
                const float4 hv = h4[j];
                gh0 = fmaf(bflo(w.x), hv.x, gh0); gh0 = fmaf(bfhi(w.x), hv.y, gh0);
                gh0 = fmaf(bflo(w.y), hv.z, gh0); gh0 = fmaf(bfhi(w.y), hv.w, gh0);
                gh1 = fmaf(bflo(w.z), hv.x, gh1); gh1 = fmaf(bfhi(w.z), hv.y, gh1);
                gh1 = fmaf(bflo(w.w), hv.z, gh1); gh1 = fmaf(bfhi(w.w), hv.w, gh1);
            }
            s_gi[r0] = gi0; s_gi[r0 + 1] = gi1;
            s_gh[r0] = gh0; s_gh[r0 + 1] = gh1;
        }
        __syncthreads();
        // ---- GRU epilogue (biases already inside s_gi/s_gh) ----
        if (tid < D) {
            const int t = tid;
            float r  = sigmoidf_(s_gi[t] + s_gh[t]);
            float z  = sigmoidf_(s_gi[D + t] + s_gh[D + t]);
            float nn = tanhf(s_gi[2 * D + t] + r * s_gh[2 * D + t]);
            float hn = (1.f - z) * nn + z * s_h[t];
            s_h[t] = hn;
            s_q[t] = hn;                  // q part of q_star
        }
        __syncthreads();

        // ---- flash attention, depth-2 pipeline, masked tail ----
        q0 = ((const float4*)s_h)[s];          // cols 4s..4s+3
        q1 = ((const float4*)s_h)[16 + s];     // cols 64+4s..64+4s+3
        m_run = NEG_HUGE; l_run = 0.f;
        acc0 = make_float4(0.f, 0.f, 0.f, 0.f);
        acc1 = make_float4(0.f, 0.f, 0.f, 0.f);

        if (FT > 0) {
            if (FT > 1) load_trip(T1_, 1);
            int t = 0;
            for (; t + 2 < FT; t += 2) {       // trips t, t+1 both full here
                compute(T0_); load_trip(T0_, t + 2);
                compute(T1_); if (t + 3 < FT) load_trip(T1_, t + 3);
            }
            if (t == FT - 1) computeM(T0_, t);
            else { compute(T0_); computeM(T1_, t + 1); }   // t+1 == FT-1
        }

        if (s == 0) { sm[g] = m_run; sl[g] = l_run; }
        __syncthreads();

        // ---- combine 16 group partials (every lane, 4-shfl tree) ----
        {
            const float mv = sm[s];
            const float lv = sl[s];
            float M = mv;
            M = fmaxf(M, __shfl_xor(M, 1, 64));
            M = fmaxf(M, __shfl_xor(M, 2, 64));
            M = fmaxf(M, __shfl_xor(M, 4, 64));
            M = fmaxf(M, __shfl_xor(M, 8, 64));
            float term = lv * __expf(mv - M);     // sentinel-safe: lv==0 there
            term += __shfl_xor(term, 1, 64);
            term += __shfl_xor(term, 2, 64);
            term += __shfl_xor(term, 4, 64);
            term += __shfl_xor(term, 8, 64);
            const float inv = 1.f / (term + 1e-16f);
            const float fac = __expf(m_run - M) * inv;  // sentinel-safe
            acc0.x *= fac; acc0.y *= fac; acc0.z *= fac; acc0.w *= fac;
            acc1.x *= fac; acc1.y *= fac; acc1.z *= fac; acc1.w *= fac;
        }
        // ---- sum the 4 groups within each wave (lanes s, s^16, s^32, s^48) --
        acc0.x += __shfl_xor(acc0.x, 16, 64); acc0.y += __shfl_xor(acc0.y, 16, 64);
        acc0.z += __shfl_xor(acc0.z, 16, 64); acc0.w += __shfl_xor(acc0.w, 16, 64);
        acc1.x += __shfl_xor(acc1.x, 16, 64); acc1.y += __shfl_xor(acc1.y, 16, 64);
        acc1.z += __shfl_xor(acc1.z, 16, 64); acc1.w += __shfl_xor(acc1.w, 16, 64);
        acc0.x += __shfl_xor(acc0.x, 32, 64); acc0.y += __shfl_xor(acc0.y, 32, 64);
        acc0.z += __shfl_xor(acc0.z, 32, 64); acc0.w += __shfl_xor(acc0.w, 32, 64);
        acc1.x += __shfl_xor(acc1.x, 32, 64); acc1.y += __shfl_xor(acc1.y, 32, 64);
        acc1.z += __shfl_xor(acc1.z, 32, 64); acc1.w += __shfl_xor(acc1.w, 32, 64);

        const int wv = tid >> 6;          // wave id 0..3
        if ((tid & 63) < 16) {
            *(float4*)&rpart[wv][s4]      = acc0;
            *(float4*)&rpart[wv][64 + s4] = acc1;
        }
        __syncthreads();
        if (tid < D) {
            float v = (rpart[0][tid] + rpart[1][tid]) + (rpart[2][tid] + rpart[3][tid]);
            s_q[D + tid] = v;             // r part of q_star (already /L)
        }
        __syncthreads();                  // s_q complete for next GRU / output
    }

    // ---- write q_star row (s_q is exactly [q | r]) ----
    if (tid < 2 * D) out[(size_t)b * (2 * D) + tid] = s_q[tid];
}

// ---------------------------------------------------------------------------
extern "C" void kernel_launch(void* const* d_in, const int* in_sizes, int n_in,
                              void* d_out, int out_size, void* d_ws, size_t ws_size,
                              hipStream_t stream) {
    const float* x    = (const float*)d_in[0];
    const int*   batch= (const int*)d_in[1];
    // d_in[2] = batch_size scalar (fixed at B=512 compile time)
    const float* Wih  = (const float*)d_in[3];
    const float* Whh  = (const float*)d_in[4];
    const float* bih  = (const float*)d_in[5];
    const float* bhh  = (const float*)d_in[6];
    const int n = in_sizes[0] / D;        // 200000

    // workspace: seg (4 KB pad) | wih_bf packed (192 KB) | whh_bf packed (96 KB)
    char* ws = (char*)d_ws;
    int* seg = (int*)ws;
    unsigned short* wih_bf = (unsigned short*)(ws + 4096);
    unsigned short* whh_bf = (unsigned short*)(ws + 4096 + (size_t)NW_IH * 2);

    const int total = NW_IH + NW_HH;      // 147456 >= B+1, covers seg too
    k_prep<<<(total + 255) / 256, 256, 0, stream>>>(Wih, Whh, batch, n, wih_bf, whh_bf, seg);
    k_set2set<<<B, 256, 0, stream>>>(x, wih_bf, whh_bf, bih, bhh, seg, (float*)d_out);
}

// Round 7
// 238.945 us; speedup vs baseline: 1.0115x; 1.0115x over previous
//
#include <hip/hip_runtime.h>
#include <hip/hip_fp16.h>
#include <math.h>
#include <float.h>

constexpr int D = 128;       // in_channels
constexpr int B = 512;       // batch_size (graphs)
constexpr int STEPS = 3;
constexpr int NW_IH = 3 * D * 2 * D;   // 98304 elems, Wih [3D][2D]
constexpr int NW_HH = 3 * D * D;       // 49152 elems, Whh [3D][D]
constexpr float NEG_HUGE = -3.402823466e38f;   // -FLT_MAX sentinel (finite: no NaN paths)

__device__ __forceinline__ float sigmoidf_(float x) { return 1.f / (1.f + __expf(-x)); }
// bf16 pair unpack from a uint: low halfword / high halfword -> float (exact)
__device__ __forceinline__ float bflo(unsigned int u) { return __uint_as_float(u << 16); }
__device__ __forceinline__ float bfhi(unsigned int u) { return __uint_as_float(u & 0xffff0000u); }
__device__ __forceinline__ unsigned short f2bf_rn(float f) {
    unsigned int u = __float_as_uint(f);
    u += 0x7fffu + ((u >> 16) & 1u);    // round-to-nearest-even
    return (unsigned short)(u >> 16);
}
__device__ __forceinline__ float4 ld4(const float* p) { return *(const float4*)p; }
__device__ __forceinline__ int imin_(int a, int b) { return a < b ? a : b; }

__device__ __forceinline__ unsigned int packh2(float a, float b) {
    union { __half2 h; unsigned int u; } c;
    c.h = __floats2half2_rn(a, b);
    return c.u;
}
__device__ __forceinline__ float2 unpackh2(unsigned int u) {
    union { unsigned int u; __half2 h; } c;
    c.u = u;
    return __half22float2(c.h);
}

// ---------------------------------------------------------------------------
// K0 (prep): weights fp32 -> bf16 (RN), row-major (R5 layout: the GRU's
// latency is hidden by 2-row ILP, not coalescing — R6 lesson), plus segment
// bounds via binary search on sorted batch[].
// ---------------------------------------------------------------------------
__global__ __launch_bounds__(256) void k_prep(const float* __restrict__ Wih,
        const float* __restrict__ Whh, const int* __restrict__ batch, int n,
        unsigned short* __restrict__ wih_bf, unsigned short* __restrict__ whh_bf,
        int* __restrict__ seg) {
    int i = blockIdx.x * blockDim.x + threadIdx.x;
    if (i < NW_IH) wih_bf[i] = f2bf_rn(Wih[i]);
    else if (i < NW_IH + NW_HH) whh_bf[i - NW_IH] = f2bf_rn(Whh[i - NW_IH]);
    if (i <= B) {
        int lo = 0, hi = n;
        while (lo < hi) { int mid = (lo + hi) >> 1; if (batch[mid] < i) lo = mid + 1; else hi = mid; }
        seg[i] = lo;
    }
}

// ---------------------------------------------------------------------------
// K1 (fused Set2Set): one block of 256 threads (4 waves) per graph.
// R6 post-mortem: GRU is latency*ILP-bound -> exact R5 GRU restored.
// R7 lever: attention is at the fp32-x BW ceiling (307MB/3 steps ~ 49us
// floor). node->lane mapping is step-invariant, so step 0's attention
// (which reads fp32 x anyway) side-writes an fp16 copy of each lane's 8
// columns (permuted col order, private layout) to workspace xh; steps 1-2
// read HALF the bytes, one uint4/node/lane, 51MB fully L3-resident.
// Same-thread store->load across barriers (vmcnt drained) -> coherent.
// WRITE_SIZE ~50MB is the xh side-write, NOT spills (watch VGPR instead).
// ---------------------------------------------------------------------------
struct Trip { float4 a0, a1, b0, b1, c0, c1, d0, d1; };

__global__ __launch_bounds__(256, 2) void k_set2set(
        const float* __restrict__ x,
        const unsigned short* __restrict__ wih_bf,
        const unsigned short* __restrict__ whh_bf,
        const float* __restrict__ bih, const float* __restrict__ bhh,
        const int* __restrict__ seg, unsigned short* __restrict__ xh,
        float* __restrict__ out) {
    __shared__ __align__(16) float s_q[2 * D];    // q_star: [q | r]
    __shared__ __align__(16) float s_h[D];
    __shared__ float s_gi[3 * D], s_gh[3 * D];
    __shared__ float sm[16], sl[16];
    __shared__ __align__(16) float rpart[4][D];   // 2 KB

    const int b = blockIdx.x;
    const int tid = threadIdx.x;
    const int start = seg[b], end = seg[b + 1];
    const int g = tid >> 4;               // node-group id 0..15
    const int s = tid & 15;               // sublane: cols [4s,4s+4) & [64+4s,64+4s+4)
    const int s4 = s * 4;                 // float offset into x row
    const int s8 = s * 8;                 // half offset into xh row (permuted layout)

    const int len = end - start;
    const int FT = (len + 63) >> 6;       // trips incl. masked last
    const int gbase = start + g;
    const int eclamp = (len > 0) ? end - 1 : start;

    float m_run, l_run;
    float4 acc0, acc1;
    float4 q0, q1;
    Trip T0_, T1_;

    auto load_trip32 = [&](Trip& T, int t) {
        const int n0 = gbase + (t << 6);
        const float* p0 = x + ((size_t)imin_(n0,      eclamp) << 7) + s4;
        const float* p1 = x + ((size_t)imin_(n0 + 16, eclamp) << 7) + s4;
        const float* p2 = x + ((size_t)imin_(n0 + 32, eclamp) << 7) + s4;
        const float* p3 = x + ((size_t)imin_(n0 + 48, eclamp) << 7) + s4;
        T.a0 = ld4(p0); T.a1 = ld4(p0 + 64);
        T.b0 = ld4(p1); T.b1 = ld4(p1 + 64);
        T.c0 = ld4(p2); T.c1 = ld4(p2 + 64);
        T.d0 = ld4(p3); T.d1 = ld4(p3 + 64);
    };
    // step-0 side-write: lane's 8 cols as 8 halfs, one 16B chunk per node.
    // Clamped nodes re-write eclamp's slot with identical data (benign).
    auto store_trip16 = [&](const Trip& T, int t) {
        const int n0 = gbase + (t << 6);
        uint4 v;
        v.x = packh2(T.a0.x, T.a0.y); v.y = packh2(T.a0.z, T.a0.w);
        v.z = packh2(T.a1.x, T.a1.y); v.w = packh2(T.a1.z, T.a1.w);
        *(uint4*)(xh + ((size_t)imin_(n0, eclamp) << 7) + s8) = v;
        v.x = packh2(T.b0.x, T.b0.y); v.y = packh2(T.b0.z, T.b0.w);
        v.z = packh2(T.b1.x, T.b1.y); v.w = packh2(T.b1.z, T.b1.w);
        *(uint4*)(xh + ((size_t)imin_(n0 + 16, eclamp) << 7) + s8) = v;
        v.x = packh2(T.c0.x, T.c0.y); v.y = packh2(T.c0.z, T.c0.w);
        v.z = packh2(T.c1.x, T.c1.y); v.w = packh2(T.c1.z, T.c1.w);
        *(uint4*)(xh + ((size_t)imin_(n0 + 32, eclamp) << 7) + s8) = v;
        v.x = packh2(T.d0.x, T.d0.y); v.y = packh2(T.d0.z, T.d0.w);
        v.z = packh2(T.d1.x, T.d1.y); v.w = packh2(T.d1.z, T.d1.w);
        *(uint4*)(xh + ((size_t)imin_(n0 + 48, eclamp) << 7) + s8) = v;
    };
    auto load_trip16 = [&](Trip& T, int t) {
        const int n0 = gbase + (t << 6);
        const uint4 va = *(const uint4*)(xh + ((size_t)imin_(n0,      eclamp) << 7) + s8);
        const uint4 vb = *(const uint4*)(xh + ((size_t)imin_(n0 + 16, eclamp) << 7) + s8);
        const uint4 vc = *(const uint4*)(xh + ((size_t)imin_(n0 + 32, eclamp) << 7) + s8);
        const uint4 vd = *(const uint4*)(xh + ((size_t)imin_(n0 + 48, eclamp) << 7) + s8);
        float2 f;
        f = unpackh2(va.x); T.a0.x = f.x; T.a0.y = f.y;
        f = unpackh2(va.y); T.a0.z = f.x; T.a0.w = f.y;
        f = unpackh2(va.z); T.a1.x = f.x; T.a1.y = f.y;
        f = unpackh2(va.w); T.a1.z = f.x; T.a1.w = f.y;
        f = unpackh2(vb.x); T.b0.x = f.x; T.b0.y = f.y;
        f = unpackh2(vb.y); T.b0.z = f.x; T.b0.w = f.y;
        f = unpackh2(vb.z); T.b1.x = f.x; T.b1.y = f.y;
        f = unpackh2(vb.w); T.b1.z = f.x; T.b1.w = f.y;
        f = unpackh2(vc.x); T.c0.x = f.x; T.c0.y = f.y;
        f = unpackh2(vc.y); T.c0.z = f.x; T.c0.w = f.y;
        f = unpackh2(vc.z); T.c1.x = f.x; T.c1.y = f.y;
        f = unpackh2(vc.w); T.c1.z = f.x; T.c1.w = f.y;
        f = unpackh2(vd.x); T.d0.x = f.x; T.d0.y = f.y;
        f = unpackh2(vd.y); T.d0.z = f.x; T.d0.w = f.y;
        f = unpackh2(vd.z); T.d1.x = f.x; T.d1.y = f.y;
        f = unpackh2(vd.w); T.d1.z = f.x; T.d1.w = f.y;
    };
    auto dot8 = [&](const float4& lo, const float4& hi) {
        float p = lo.x * q0.x;
        p = fmaf(lo.y, q0.y, p); p = fmaf(lo.z, q0.z, p); p = fmaf(lo.w, q0.w, p);
        p = fmaf(hi.x, q1.x, p); p = fmaf(hi.y, q1.y, p);
        p = fmaf(hi.z, q1.z, p); p = fmaf(hi.w, q1.w, p);
        return p;
    };
    auto compute_core = [&](const Trip& T, bool masked, int t) {
        float p0 = dot8(T.a0, T.a1);
        float p1 = dot8(T.b0, T.b1);
        float p2 = dot8(T.c0, T.c1);
        float p3 = dot8(T.d0, T.d1);
        p0 += __shfl_xor(p0, 1, 64); p1 += __shfl_xor(p1, 1, 64);
        p2 += __shfl_xor(p2, 1, 64); p3 += __shfl_xor(p3, 1, 64);
        p0 += __shfl_xor(p0, 2, 64); p1 += __shfl_xor(p1, 2, 64);
        p2 += __shfl_xor(p2, 2, 64); p3 += __shfl_xor(p3, 2, 64);
        p0 += __shfl_xor(p0, 4, 64); p1 += __shfl_xor(p1, 4, 64);
        p2 += __shfl_xor(p2, 4, 64); p3 += __shfl_xor(p3, 4, 64);
        p0 += __shfl_xor(p0, 8, 64); p1 += __shfl_xor(p1, 8, 64);
        p2 += __shfl_xor(p2, 8, 64); p3 += __shfl_xor(p3, 8, 64);
        bool m0 = true, m1 = true, m2 = true, m3 = true;
        float h0 = p0, h1 = p1, h2 = p2, h3 = p3;
        if (masked) {
            const int n0 = gbase + (t << 6);
            m0 = n0 < end; m1 = n0 + 16 < end; m2 = n0 + 32 < end; m3 = n0 + 48 < end;
            h0 = m0 ? p0 : NEG_HUGE; h1 = m1 ? p1 : NEG_HUGE;
            h2 = m2 ? p2 : NEG_HUGE; h3 = m3 ? p3 : NEG_HUGE;
        }
        float nm = fmaxf(m_run, fmaxf(fmaxf(h0, h1), fmaxf(h2, h3)));
        float sc = __expf(m_run - nm);            // 0 while m_run sentinel
        float e0 = __expf(p0 - nm), e1 = __expf(p1 - nm);
        float e2 = __expf(p2 - nm), e3 = __expf(p3 - nm);
        if (masked) {
            e0 = m0 ? e0 : 0.f; e1 = m1 ? e1 : 0.f;
            e2 = m2 ? e2 : 0.f; e3 = m3 ? e3 : 0.f;
        }
        l_run = fmaf(l_run, sc, (e0 + e1) + (e2 + e3));
        acc0.x = fmaf(acc0.x, sc, fmaf(e0, T.a0.x, fmaf(e1, T.b0.x, fmaf(e2, T.c0.x, e3 * T.d0.x))));
        acc0.y = fmaf(acc0.y, sc, fmaf(e0, T.a0.y, fmaf(e1, T.b0.y, fmaf(e2, T.c0.y, e3 * T.d0.y))));
        acc0.z = fmaf(acc0.z, sc, fmaf(e0, T.a0.z, fmaf(e1, T.b0.z, fmaf(e2, T.c0.z, e3 * T.d0.z))));
        acc0.w = fmaf(acc0.w, sc, fmaf(e0, T.a0.w, fmaf(e1, T.b0.w, fmaf(e2, T.c0.w, e3 * T.d0.w))));
        acc1.x = fmaf(acc1.x, sc, fmaf(e0, T.a1.x, fmaf(e1, T.b1.x, fmaf(e2, T.c1.x, e3 * T.d1.x))));
        acc1.y = fmaf(acc1.y, sc, fmaf(e0, T.a1.y, fmaf(e1, T.b1.y, fmaf(e2, T.c1.y, e3 * T.d1.y))));
        acc1.z = fmaf(acc1.z, sc, fmaf(e0, T.a1.z, fmaf(e1, T.b1.z, fmaf(e2, T.c1.z, e3 * T.d1.z))));
        acc1.w = fmaf(acc1.w, sc, fmaf(e0, T.a1.w, fmaf(e1, T.b1.w, fmaf(e2, T.c1.w, e3 * T.d1.w))));
        m_run = nm;
    };
    auto compute  = [&](const Trip& T)        { compute_core(T, false, 0); };
    auto computeM = [&](const Trip& T, int t) { compute_core(T, true,  t); };

    if (tid < 2 * D) s_q[tid] = 0.f;
    if (tid < D) s_h[tid] = 0.f;
    __syncthreads();

    for (int step = 0; step < STEPS; ++step) {
        // prefetch trip 0 under the GRU (x / xh are step-invariant; no LDS dep)
        if (FT > 0) { if (step == 0) load_trip32(T0_, 0); else load_trip16(T0_, 0); }

        if (step == 0) {
            // q_star = 0 and h = 0: gi = b_ih, gh = b_hh exactly -> skip matvec
            for (int i = tid; i < 3 * D; i += 256) { s_gi[i] = bih[i]; s_gh[i] = bhh[i]; }
        } else if (tid < 192) {
            // ---- GRU gate rows: threads 0..191, rows 2t and 2t+1 (ILP 2) ----
            const int r0 = tid * 2, r1 = r0 + 1;
            float gi0 = bih[r0], gi1 = bih[r1];
            float gh0 = bhh[r0], gh1 = bhh[r1];
            const float4* q4 = (const float4*)s_q;
            const float4* h4 = (const float4*)s_h;
            const uint4* w0 = (const uint4*)(wih_bf + (size_t)r0 * (2 * D));
            const uint4* w1 = (const uint4*)(wih_bf + (size_t)r1 * (2 * D));
#pragma unroll 4
            for (int c = 0; c < 32; ++c) {        // 256 cols of Wih, 8/iter
                uint4 wa = w0[c], wb = w1[c];
                float4 qa = q4[2 * c], qb = q4[2 * c + 1];
                gi0 = fmaf(bflo(wa.x), qa.x, gi0); gi0 = fmaf(bfhi(wa.x), qa.y, gi0);
                gi0 = fmaf(bflo(wa.y), qa.z, gi0); gi0 = fmaf(bfhi(wa.y), qa.w, gi0);
                gi0 = fmaf(bflo(wa.z), qb.x, gi0); gi0 = fmaf(bfhi(wa.z), qb.y, gi0);
                gi0 = fmaf(bflo(wa.w), qb.z, gi0); gi0 = fmaf(bfhi(wa.w), qb.w, gi0);
                gi1 = fmaf(bflo(wb.x), qa.x, gi1); gi1 = fmaf(bfhi(wb.x), qa.y, gi1);
                gi1 = fmaf(bflo(wb.y), qa.z, gi1); gi1 = fmaf(bfhi(wb.y), qa.w, gi1);
                gi1 = fmaf(bflo(wb.z), qb.x, gi1); gi1 = fmaf(bfhi(wb.z), qb.y, gi1);
                gi1 = fmaf(bflo(wb.w), qb.z, gi1); gi1 = fmaf(bfhi(wb.w), qb.w, gi1);
            }
            const uint4* v0 = (const uint4*)(whh_bf + (size_t)r0 * D);
            const uint4* v1 = (const uint4*)(whh_bf + (size_t)r1 * D);
#pragma unroll 4
            for (int c = 0; c < 16; ++c) {        // 128 cols of Whh
                uint4 wa = v0[c], wb = v1[c];
                float4 ha = h4[2 * c], hb = h4[2 * c + 1];
                gh0 = fmaf(bflo(wa.x), ha.x, gh0); gh0 = fmaf(bfhi(wa.x), ha.y, gh0);
                gh0 = fmaf(bflo(wa.y), ha.z, gh0); gh0 = fmaf(bfhi(wa.y), ha.w, gh0);
                gh0 = fmaf(bflo(wa.z), hb.x, gh0); gh0 = fmaf(bfhi(wa.z), hb.y, gh0);
                gh0 = fmaf(bflo(wa.w), hb.z, gh0); gh0 = fmaf(bfhi(wa.w), hb.w, gh0);
                gh1 = fmaf(bflo(wb.x), ha.x, gh1); gh1 = fmaf(bfhi(wb.x), ha.y, gh1);
                gh1 = fmaf(bflo(wb.y), ha.z, gh1); gh1 = fmaf(bfhi(wb.y), ha.w, gh1);
                gh1 = fmaf(bflo(wb.z), hb.x, gh1); gh1 = fmaf(bfhi(wb.z), hb.y, gh1);
                gh1 = fmaf(bflo(wb.w), hb.z, gh1); gh1 = fmaf(bfhi(wb.w), hb.w, gh1);
            }
            s_gi[r0] = gi0; s_gi[r1] = gi1;
            s_gh[r0] = gh0; s_gh[r1] = gh1;
        }
        __syncthreads();
        // ---- GRU epilogue (biases already inside s_gi/s_gh) ----
        if (tid < D) {
            const int t = tid;
            float r  = sigmoidf_(s_gi[t] + s_gh[t]);
            float z  = sigmoidf_(s_gi[D + t] + s_gh[D + t]);
            float nn = tanhf(s_gi[2 * D + t] + r * s_gh[2 * D + t]);
            float hn = (1.f - z) * nn + z * s_h[t];
            s_h[t] = hn;
            s_q[t] = hn;                  // q part of q_star
        }
        __syncthreads();

        // ---- flash attention, depth-2 pipeline, masked tail ----
        q0 = ((const float4*)s_h)[s];          // cols 4s..4s+3
        q1 = ((const float4*)s_h)[16 + s];     // cols 64+4s..64+4s+3
        m_run = NEG_HUGE; l_run = 0.f;
        acc0 = make_float4(0.f, 0.f, 0.f, 0.f);
        acc1 = make_float4(0.f, 0.f, 0.f, 0.f);

        if (FT > 0) {
            if (step == 0) {
                // fp32 reads + fp16 side-write (store before the buffer reload)
                if (FT > 1) load_trip32(T1_, 1);
                int t = 0;
                for (; t + 2 < FT; t += 2) {
                    compute(T0_); store_trip16(T0_, t); load_trip32(T0_, t + 2);
                    compute(T1_); store_trip16(T1_, t + 1);
                    if (t + 3 < FT) load_trip32(T1_, t + 3);
                }
                if (t == FT - 1) { computeM(T0_, t); store_trip16(T0_, t); }
                else {
                    compute(T0_); store_trip16(T0_, t);
                    computeM(T1_, t + 1); store_trip16(T1_, t + 1);
                }
            } else {
                if (FT > 1) load_trip16(T1_, 1);
                int t = 0;
                for (; t + 2 < FT; t += 2) {
                    compute(T0_); load_trip16(T0_, t + 2);
                    compute(T1_); if (t + 3 < FT) load_trip16(T1_, t + 3);
                }
                if (t == FT - 1) computeM(T0_, t);
                else { compute(T0_); computeM(T1_, t + 1); }
            }
        }

        if (s == 0) { sm[g] = m_run; sl[g] = l_run; }
        __syncthreads();

        // ---- combine 16 group partials (every lane, 4-shfl tree) ----
        {
            const float mv = sm[s];
            const float lv = sl[s];
            float M = mv;
            M = fmaxf(M, __shfl_xor(M, 1, 64));
            M = fmaxf(M, __shfl_xor(M, 2, 64));
            M = fmaxf(M, __shfl_xor(M, 4, 64));
            M = fmaxf(M, __shfl_xor(M, 8, 64));
            float term = lv * __expf(mv - M);     // sentinel-safe: lv==0 there
            term += __shfl_xor(term, 1, 64);
            term += __shfl_xor(term, 2, 64);
            term += __shfl_xor(term, 4, 64);
            term += __shfl_xor(term, 8, 64);
            const float inv = 1.f / (term + 1e-16f);
            const float fac = __expf(m_run - M) * inv;  // sentinel-safe
            acc0.x *= fac; acc0.y *= fac; acc0.z *= fac; acc0.w *= fac;
            acc1.x *= fac; acc1.y *= fac; acc1.z *= fac; acc1.w *= fac;
        }
        // ---- sum the 4 groups within each wave (lanes s, s^16, s^32, s^48) --
        acc0.x += __shfl_xor(acc0.x, 16, 64); acc0.y += __shfl_xor(acc0.y, 16, 64);
        acc0.z += __shfl_xor(acc0.z, 16, 64); acc0.w += __shfl_xor(acc0.w, 16, 64);
        acc1.x += __shfl_xor(acc1.x, 16, 64); acc1.y += __shfl_xor(acc1.y, 16, 64);
        acc1.z += __shfl_xor(acc1.z, 16, 64); acc1.w += __shfl_xor(acc1.w, 16, 64);
        acc0.x += __shfl_xor(acc0.x, 32, 64); acc0.y += __shfl_xor(acc0.y, 32, 64);
        acc0.z += __shfl_xor(acc0.z, 32, 64); acc0.w += __shfl_xor(acc0.w, 32, 64);
        acc1.x += __shfl_xor(acc1.x, 32, 64); acc1.y += __shfl_xor(acc1.y, 32, 64);
        acc1.z += __shfl_xor(acc1.z, 32, 64); acc1.w += __shfl_xor(acc1.w, 32, 64);

        const int wv = tid >> 6;          // wave id 0..3
        if ((tid & 63) < 16) {
            *(float4*)&rpart[wv][s4]      = acc0;
            *(float4*)&rpart[wv][64 + s4] = acc1;
        }
        __syncthreads();
        if (tid < D) {
            float v = (rpart[0][tid] + rpart[1][tid]) + (rpart[2][tid] + rpart[3][tid]);
            s_q[D + tid] = v;             // r part of q_star (already /L)
        }
        __syncthreads();                  // s_q complete for next GRU / output
    }

    // ---- write q_star row (s_q is exactly [q | r]) ----
    if (tid < 2 * D) out[(size_t)b * (2 * D) + tid] = s_q[tid];
}

// ---------------------------------------------------------------------------
extern "C" void kernel_launch(void* const* d_in, const int* in_sizes, int n_in,
                              void* d_out, int out_size, void* d_ws, size_t ws_size,
                              hipStream_t stream) {
    const float* x    = (const float*)d_in[0];
    const int*   batch= (const int*)d_in[1];
    // d_in[2] = batch_size scalar (fixed at B=512 compile time)
    const float* Wih  = (const float*)d_in[3];
    const float* Whh  = (const float*)d_in[4];
    const float* bih  = (const float*)d_in[5];
    const float* bhh  = (const float*)d_in[6];
    const int n = in_sizes[0] / D;        // 200000

    // workspace: seg (4 KB) | wih_bf (192 KB) | whh_bf (96 KB) | xh fp16 (~51.2 MB)
    char* ws = (char*)d_ws;
    int* seg = (int*)ws;
    unsigned short* wih_bf = (unsigned short*)(ws + 4096);
    unsigned short* whh_bf = (unsigned short*)(ws + 4096 + (size_t)NW_IH * 2);
    unsigned short* xh     = (unsigned short*)(ws + 4096 + (size_t)NW_IH * 2 + (size_t)NW_HH * 2);

    const int total = NW_IH + NW_HH;      // 147456 >= B+1, covers seg too
    k_prep<<<(total + 255) / 256, 256, 0, stream>>>(Wih, Whh, batch, n, wih_bf, whh_bf, seg);
    k_set2set<<<B, 256, 0, stream>>>(x, wih_bf, whh_bf, bih, bhh, seg, xh, (float*)d_out);
}